// Round 5
// baseline (4484.138 us; speedup 1.0000x reference)
//
// Encoder-decoder LSTM + dot attention + linear, MI355X fp32.  R5
// R4 post-mortem: scan is RT-bound (~2500cyc/step exposed publish->poll), FMA
// micro-opts neutral. This round: TWO chains per 8-block group, software-
// pipelined so each chain's L3 round trip hides behind the OTHER chain's
// compute. 32 pairs x 8 slices (grid 256; slices of a pair share an XCD via
// blk = pair + 32*sl, %8 = pair%8). Block owns 32 h-dims of both chains:
// 128 rows x 256 k weights in VGPRs (64/thread). 3 barriers/iter.
// Tagged parity-2 exchange protocol unchanged (fence-free relaxed atomics).
#include <hip/hip_runtime.h>
#include <math.h>

#define HD 256
#define GD 1024   // 4*H
#define TT 1024
#define BB 64
#define NT 512    // scan block size

__device__ __forceinline__ float sig_(float x)  { return 1.f / (1.f + __expf(-x)); }
__device__ __forceinline__ float tanh_(float x) { return 1.f - 2.f / (1.f + __expf(2.f * x)); }

// ---------------- prep: transpose Whh -> [k][j], bias sums, zero exchange ----------------
__global__ __launch_bounds__(256) void prep_kernel(
    const float* __restrict__ eW, const float* __restrict__ eb1, const float* __restrict__ eb2,
    const float* __restrict__ dW, const float* __restrict__ db1, const float* __restrict__ db2,
    float* __restrict__ WTe, float* __restrict__ WTd,
    float* __restrict__ be, float* __restrict__ bd,
    unsigned long long* __restrict__ ex_all)   // [2 scans][B][2][256]
{
    int idx = blockIdx.x * 256 + threadIdx.x;
    if (idx < GD * HD) {
        int j = idx / HD, k = idx % HD;      // Whh[j][k]
        WTe[k * GD + j] = eW[idx];
        WTd[k * GD + j] = dW[idx];
    }
    if (idx < GD) {
        be[idx] = eb1[idx] + eb2[idx];
        bd[idx] = db1[idx] + db2[idx];
    }
    if (idx < 2 * BB * 2 * 256) ex_all[idx] = 0ULL;   // tags=0 (< any t+1)
}

// ---------------- LSTM scan: 2 chains / 8 blocks, pipelined tagged exchange ----------
// blk = pair + 32*sl ; pair in [0,32), sl in [0,8). Chains b0=2*pair, b1=2*pair+1.
// Block owns h dims [32sl, 32sl+32) for BOTH chains: gate rows {i,f,g,o}x[32sl,32sl+32).
// thread: r = tid>>2 (row 0..127, = gate*32+dim), s = tid&3 (k-quarter).
__global__ __launch_bounds__(NT, 2) void lstm_scan_pair(
    const float* __restrict__ x,       // [B,T]
    const float* __restrict__ Wih,     // [4H]
    const float* __restrict__ bias,    // [4H] (bih+bhh)
    const float* __restrict__ WT,      // [H][4H]
    const float* __restrict__ h_init,  // nullptr, or enc_states (reads [b][T-1][:])
    float* __restrict__ states,        // [B,T,H]
    unsigned long long* __restrict__ ex)  // [B][2][256] tagged slots
{
    const int pair = blockIdx.x & 31;
    const int sl   = blockIdx.x >> 5;
    const int b0 = 2 * pair, b1 = 2 * pair + 1;
    const int tid = threadIdx.x;
    const int r    = tid >> 2;          // 0..127
    const int s    = tid & 3;           // k-quarter
    const int gate = r >> 5;            // 0:i 1:f 2:g 3:o
    const int dim  = r & 31;
    const int jg   = gate * 256 + sl * 32 + dim;   // global gate row

    __shared__ float h0s[4][264];       // partition q holds h0[64q..64q+64), 8-bank stagger
    __shared__ float h1s[4][264];
    __shared__ float act0[128];
    __shared__ float act1[128];
    __shared__ float x_s[2][TT];

    // ---- weights: row jg, k in [64s,64s+64): 64 VGPRs ----
    float4 w[16];
    {
        const float* bk = WT + (size_t)(s * 64) * GD + jg;
        #pragma unroll
        for (int i = 0; i < 16; ++i) {
            const float* p0 = bk + (size_t)(4 * i) * GD;
            w[i] = make_float4(p0[0], p0[GD], p0[2 * GD], p0[3 * GD]);
        }
    }
    const float wih = Wih[jg], bj = bias[jg];

    for (int i = tid; i < TT; i += NT) {
        x_s[0][i] = x[b0 * TT + i];
        x_s[1][i] = x[b1 * TT + i];
    }
    if (tid < 256) {
        float hv = h_init ? h_init[((size_t)b0 * TT + (TT - 1)) * HD + tid] : 0.f;
        h0s[tid >> 6][tid & 63] = hv;
    } else {
        int gd = tid - 256;
        float hv = h_init ? h_init[((size_t)b1 * TT + (TT - 1)) * HD + gd] : 0.f;
        h1s[gd >> 6][gd & 63] = hv;
    }
    float c0 = 0.f, c1 = 0.f;   // live in tid<32 (c0) and tid in [256,288) (c1)
    __syncthreads();

    unsigned long long* ex0 = ex + (size_t)b0 * 2 * 256;
    unsigned long long* ex1 = ex + (size_t)b1 * 2 * 256;

    for (int t = 0; t < TT; ++t) {
        // ---------- phase 1: FMA ch0 ; waves 4-7 then poll h1(t) ----------
        {
            const float xt = x_s[0][t];
            float a = (s == 0) ? fmaf(xt, wih, bj) : 0.f;
            const float4* h4 = (const float4*)&h0s[s][0];
            #pragma unroll
            for (int i = 0; i < 16; ++i) {
                float4 hv = h4[i];
                a = fmaf(hv.x, w[i].x, a); a = fmaf(hv.y, w[i].y, a);
                a = fmaf(hv.z, w[i].z, a); a = fmaf(hv.w, w[i].w, a);
            }
            a += __shfl_xor(a, 1); a += __shfl_xor(a, 2);
            if (s == 0) act0[r] = (gate == 2) ? tanh_(a) : sig_(a);
        }
        if (t > 0 && tid >= 288) {
            const int u  = tid - 288;
            const int gd = u + (u >= sl * 32 ? 32 : 0);
            unsigned long long* slot = ex1 + (size_t)(t & 1) * 256 + gd;
            unsigned long long v;
            do { v = __hip_atomic_load(slot, __ATOMIC_RELAXED, __HIP_MEMORY_SCOPE_AGENT); }
            while ((unsigned)(v >> 32) != (unsigned)t);
            h1s[gd >> 6][gd & 63] = __uint_as_float((unsigned)v);
        }
        __syncthreads();

        // ---------- phase 2: update+publish ch0 (wave 0) ; FMA ch1 (all) ----------
        if (tid < 32) {
            float gi = act0[tid], gf = act0[32 + tid], gg = act0[64 + tid], go = act0[96 + tid];
            c0 = fmaf(gf, c0, gi * gg);
            float h = go * tanh_(c0);
            const int gd = sl * 32 + tid;
            unsigned long long pk = ((unsigned long long)(unsigned)(t + 1) << 32)
                                  | (unsigned long long)__float_as_uint(h);
            __hip_atomic_store(ex0 + (size_t)((t + 1) & 1) * 256 + gd, pk,
                               __ATOMIC_RELAXED, __HIP_MEMORY_SCOPE_AGENT);
            h0s[gd >> 6][gd & 63] = h;
            states[((size_t)(b0 * TT + t)) * HD + gd] = h;
        }
        {
            const float xt = x_s[1][t];
            float a = (s == 0) ? fmaf(xt, wih, bj) : 0.f;
            const float4* h4 = (const float4*)&h1s[s][0];
            #pragma unroll
            for (int i = 0; i < 16; ++i) {
                float4 hv = h4[i];
                a = fmaf(hv.x, w[i].x, a); a = fmaf(hv.y, w[i].y, a);
                a = fmaf(hv.z, w[i].z, a); a = fmaf(hv.w, w[i].w, a);
            }
            a += __shfl_xor(a, 1); a += __shfl_xor(a, 2);
            if (s == 0) act1[r] = (gate == 2) ? tanh_(a) : sig_(a);
        }
        __syncthreads();

        // ---------- phase 3: update+publish ch1 (wave 4) ; waves 0-3 poll h0(t+1) ----------
        if (tid >= 256 && tid < 288) {
            const int l = tid - 256;
            float gi = act1[l], gf = act1[32 + l], gg = act1[64 + l], go = act1[96 + l];
            c1 = fmaf(gf, c1, gi * gg);
            float h = go * tanh_(c1);
            const int gd = sl * 32 + l;
            unsigned long long pk = ((unsigned long long)(unsigned)(t + 1) << 32)
                                  | (unsigned long long)__float_as_uint(h);
            __hip_atomic_store(ex1 + (size_t)((t + 1) & 1) * 256 + gd, pk,
                               __ATOMIC_RELAXED, __HIP_MEMORY_SCOPE_AGENT);
            h1s[gd >> 6][gd & 63] = h;
            states[((size_t)(b1 * TT + t)) * HD + gd] = h;
        }
        if (tid >= 32 && tid < 256 && t < TT - 1) {
            const int u  = tid - 32;
            const int gd = u + (u >= sl * 32 ? 32 : 0);
            unsigned long long* slot = ex0 + (size_t)((t + 1) & 1) * 256 + gd;
            unsigned long long v;
            do { v = __hip_atomic_load(slot, __ATOMIC_RELAXED, __HIP_MEMORY_SCOPE_AGENT); }
            while ((unsigned)(v >> 32) != (unsigned)(t + 1));
            h0s[gd >> 6][gd & 63] = __uint_as_float((unsigned)v);
        }
        __syncthreads();
    }
}

// ---------------- proj: ew[b][t]=E·w1, hw[b][t]=Hx·w2 (one wave per row) ----------------
__global__ __launch_bounds__(256) void proj_kernel(
    const float* __restrict__ enc_states, const float* __restrict__ dec_hs,
    const float* __restrict__ linW, float* __restrict__ ew, float* __restrict__ hw)
{
    const int lane = threadIdx.x & 63;
    const int wid  = blockIdx.x * 4 + (threadIdx.x >> 6);
    const int nw   = gridDim.x * 4;
    const float4 w1 = ((const float4*)linW)[lane];
    const float4 w2 = ((const float4*)(linW + HD))[lane];
    for (int o = wid; o < BB * TT; o += nw) {
        float4 v1 = ((const float4*)(enc_states + (size_t)o * HD))[lane];
        float4 v2 = ((const float4*)(dec_hs     + (size_t)o * HD))[lane];
        float s1 = v1.x * w1.x + v1.y * w1.y + v1.z * w1.z + v1.w * w1.w;
        float s2 = v2.x * w2.x + v2.y * w2.y + v2.z * w2.z + v2.w * w2.w;
        #pragma unroll
        for (int m = 1; m < 64; m <<= 1) {
            s1 += __shfl_xor(s1, m);
            s2 += __shfl_xor(s2, m);
        }
        if (lane == 0) { ew[o] = s1; hw[o] = s2; }
    }
}

// ---------------- attention: 32 td rows/block, 4x8 register tile ----------------
#define TD2  32    // td rows per block
#define TEC2 256   // te chunk
#define KC2  32    // k chunk
__global__ __launch_bounds__(256) void attn_kernel(
    const float* __restrict__ enc_states,  // [B][T][H]
    const float* __restrict__ dec_hs,      // [B][T][H]
    const float* __restrict__ ew, const float* __restrict__ hw,
    const float* __restrict__ lin_b,
    float* __restrict__ out)               // [B][T]
{
    const int b   = blockIdx.y;
    const int td0 = blockIdx.x * TD2;
    const int tid = threadIdx.x;
    const int tdt = tid >> 5;   // 0..7 (4 td rows each)
    const int tet = tid & 31;   // 0..31

    __shared__ float Hx[HD][TD2 + 4];   // stride 36: rows 16B-aligned
    __shared__ float E[KC2][TEC2];

    {
        const int td = tid >> 3;
        const int kc = (tid & 7) * 32;
        const float* src = dec_hs + ((size_t)b * TT + td0 + td) * HD + kc;
        #pragma unroll
        for (int qq = 0; qq < 8; ++qq) {
            float4 v = ((const float4*)(src + qq * 4))[0];
            Hx[kc + qq * 4 + 0][td] = v.x;
            Hx[kc + qq * 4 + 1][td] = v.y;
            Hx[kc + qq * 4 + 2][td] = v.z;
            Hx[kc + qq * 4 + 3][td] = v.w;
        }
    }

    float M[4]  = {-1e30f, -1e30f, -1e30f, -1e30f};
    float Nm[4] = {0.f, 0.f, 0.f, 0.f};
    float Dn[4] = {0.f, 0.f, 0.f, 0.f};

    for (int tc = 0; tc < TT / TEC2; ++tc) {
        const int te0 = tc * TEC2;
        float S[4][8] = {{0.f}};
        for (int kc = 0; kc < HD / KC2; ++kc) {
            const int k0 = kc * KC2;
            __syncthreads();
            {   // stage E chunk: thread = te row, 32 consecutive k
                const float* src = enc_states + ((size_t)b * TT + te0 + tid) * HD + k0;
                #pragma unroll
                for (int qq = 0; qq < 8; ++qq) {
                    float4 v = ((const float4*)(src + qq * 4))[0];
                    E[qq * 4 + 0][tid] = v.x;
                    E[qq * 4 + 1][tid] = v.y;
                    E[qq * 4 + 2][tid] = v.z;
                    E[qq * 4 + 3][tid] = v.w;
                }
            }
            __syncthreads();
            #pragma unroll 4
            for (int k = 0; k < KC2; ++k) {
                const float4 hx4 = *(const float4*)(&Hx[k0 + k][tdt * 4]);
                #pragma unroll
                for (int i = 0; i < 8; ++i) {
                    const float e = E[k][tet + 32 * i];
                    S[0][i] = fmaf(hx4.x, e, S[0][i]);
                    S[1][i] = fmaf(hx4.y, e, S[1][i]);
                    S[2][i] = fmaf(hx4.z, e, S[2][i]);
                    S[3][i] = fmaf(hx4.w, e, S[3][i]);
                }
            }
        }
        float ewv[8];
        #pragma unroll
        for (int i = 0; i < 8; ++i) ewv[i] = ew[(size_t)b * TT + te0 + tet + 32 * i];
        #pragma unroll
        for (int r = 0; r < 4; ++r) {
            float cm = S[r][0];
            #pragma unroll
            for (int i = 1; i < 8; ++i) cm = fmaxf(cm, S[r][i]);
            #pragma unroll
            for (int m = 1; m < 32; m <<= 1) cm = fmaxf(cm, __shfl_xor(cm, m));
            const float newM  = fmaxf(M[r], cm);
            const float scale = __expf(M[r] - newM);
            float nl = 0.f, dl = 0.f;
            #pragma unroll
            for (int i = 0; i < 8; ++i) {
                const float p = __expf(S[r][i] - newM);
                dl += p;
                nl = fmaf(p, ewv[i], nl);
            }
            #pragma unroll
            for (int m = 1; m < 32; m <<= 1) {
                nl += __shfl_xor(nl, m);
                dl += __shfl_xor(dl, m);
            }
            Nm[r] = Nm[r] * scale + nl;
            Dn[r] = Dn[r] * scale + dl;
            M[r]  = newM;
        }
    }

    if (tet == 0) {
        const float lb = lin_b[0];
        #pragma unroll
        for (int r = 0; r < 4; ++r) {
            const int td = td0 + tdt * 4 + r;
            out[(size_t)b * TT + td] = Nm[r] / Dn[r] + hw[(size_t)b * TT + td] + lb;
        }
    }
}

extern "C" void kernel_launch(void* const* d_in, const int* in_sizes, int n_in,
                              void* d_out, int out_size, void* d_ws, size_t ws_size,
                              hipStream_t stream)
{
    const float* x    = (const float*)d_in[0];
    const float* eWih = (const float*)d_in[1];
    const float* eWhh = (const float*)d_in[2];
    const float* ebih = (const float*)d_in[3];
    const float* ebhh = (const float*)d_in[4];
    const float* dWih = (const float*)d_in[5];
    const float* dWhh = (const float*)d_in[6];
    const float* dbih = (const float*)d_in[7];
    const float* dbhh = (const float*)d_in[8];
    const float* linW = (const float*)d_in[9];
    const float* linb = (const float*)d_in[10];
    float* out = (float*)d_out;

    float* p = (float*)d_ws;
    float* WTe = p;        p += (size_t)GD * HD;
    float* WTd = p;        p += (size_t)GD * HD;
    float* be  = p;        p += GD;
    float* bd  = p;        p += GD;
    float* enc_states = p; p += (size_t)BB * TT * HD;
    float* dec_hs = p;     p += (size_t)BB * TT * HD;
    float* ew = p;         p += (size_t)BB * TT;
    float* hw = p;         p += (size_t)BB * TT;
    unsigned long long* ex_e = (unsigned long long*)p; p += (size_t)BB * 2 * 256 * 2;
    unsigned long long* ex_d = (unsigned long long*)p; p += (size_t)BB * 2 * 256 * 2;

    prep_kernel<<<(GD * HD + 255) / 256, 256, 0, stream>>>(
        eWhh, ebih, ebhh, dWhh, dbih, dbhh, WTe, WTd, be, bd, ex_e);

    {
        const float* hi = nullptr;
        void* args[] = {(void*)&x, (void*)&eWih, (void*)&be, (void*)&WTe,
                        (void*)&hi, (void*)&enc_states, (void*)&ex_e};
        hipLaunchCooperativeKernel((void*)lstm_scan_pair, dim3(256), dim3(NT),
                                   args, 0, stream);
    }
    {
        const float* hi = enc_states;
        void* args[] = {(void*)&x, (void*)&dWih, (void*)&bd, (void*)&WTd,
                        (void*)&hi, (void*)&dec_hs, (void*)&ex_d};
        hipLaunchCooperativeKernel((void*)lstm_scan_pair, dim3(256), dim3(NT),
                                   args, 0, stream);
    }

    proj_kernel<<<256, 256, 0, stream>>>(enc_states, dec_hs, linW, ew, hw);
    attn_kernel<<<dim3(TT / TD2, BB), 256, 0, stream>>>(enc_states, dec_hs, ew, hw, linb, out);
}

// Round 6
// 3940.914 us; speedup vs baseline: 1.1378x; 1.1378x over previous
//
// Encoder-decoder LSTM + dot attention + linear, MI355X fp32.  R6
// R5 post-mortem: chain-pipelining over shared HW can't beat C=1 (wall =
// 1024*(C*comp + max(0, RT-(C-1)*comp))) -> reverted to R4 scan structure.
// R6: shrink RT itself. 4 blocks of a chain share an XCD (%8 round-robin,
// stride 64 = 0 mod 8) -> per-XCD L2 is a shared coherent point. Producer
// dual-publishes tagged {tag,h} 8B: sc0 store (L2 "fast" slot) + agent-scope
// store (MALL "slow" slot, R4-proven). Consumers poll fast slot via asm
// global_load_dwordx2 sc0 (L1-bypass, L2-hit ~200cyc); sticky per-thread
// valve (96 spins) falls back to slow-slot polling => worst case == R4.
#include <hip/hip_runtime.h>
#include <math.h>

#define HD 256
#define GD 1024   // 4*H
#define TT 1024
#define BB 64
#define NT 512    // scan block size

__device__ __forceinline__ float sig_(float x)  { return 1.f / (1.f + __expf(-x)); }
__device__ __forceinline__ float tanh_(float x) { return 1.f - 2.f / (1.f + __expf(2.f * x)); }

// ---------------- prep: transpose Whh -> [k][j], bias sums, zero exchange ----------------
__global__ __launch_bounds__(256) void prep_kernel(
    const float* __restrict__ eW, const float* __restrict__ eb1, const float* __restrict__ eb2,
    const float* __restrict__ dW, const float* __restrict__ db1, const float* __restrict__ db2,
    float* __restrict__ WTe, float* __restrict__ WTd,
    float* __restrict__ be, float* __restrict__ bd,
    unsigned long long* __restrict__ ex_all)   // [4][B][2][256]: {fast,slow} x {enc,dec}
{
    int idx = blockIdx.x * 256 + threadIdx.x;
    if (idx < GD * HD) {
        int j = idx / HD, k = idx % HD;      // Whh[j][k]
        WTe[k * GD + j] = eW[idx];
        WTd[k * GD + j] = dW[idx];
    }
    if (idx < GD) {
        be[idx] = eb1[idx] + eb2[idx];
        bd[idx] = db1[idx] + db2[idx];
    }
    if (idx < 4 * BB * 2 * 256) ex_all[idx] = 0ULL;   // tags=0 (< any t+1)
}

// ---------------- LSTM scan: 4 blocks/chain, weights in VGPRs, tagged exchange ----------
// block = (b = blk&63, q = blk>>6); q owns hidden dims [64q, 64q+64)
// thread: s = tid&3 (k-quarter), jj = tid>>2 (row-pair 2jj,2jj+1 of block's 256 gate rows)
__global__ __launch_bounds__(NT, 2) void lstm_scan_coop(
    const float* __restrict__ x,       // [B,T]
    const float* __restrict__ Wih,     // [4H]
    const float* __restrict__ bias,    // [4H] (bih+bhh)
    const float* __restrict__ WT,      // [H][4H]
    const float* __restrict__ h_init,  // nullptr, or enc_states (reads [b][T-1][:])
    float* __restrict__ states,        // [B,T,H]
    unsigned long long* __restrict__ exf,  // [B][2][256] fast slots (XCD-L2)
    unsigned long long* __restrict__ exs)  // [B][2][256] slow slots (MALL, R4 path)
{
    const int b   = blockIdx.x & 63;
    const int q   = blockIdx.x >> 6;
    const int tid = threadIdx.x;
    const int s   = tid & 3;            // k-quarter
    const int jj  = tid >> 2;           // 0..127
    const int gate = jj >> 5;           // 0:i 1:f 2:g 3:o
    const int kk0  = (jj & 31) * 2;     // local dim pair
    const int r0   = gate * 64 + kk0;   // local row in [0,256)
    const int jg0  = gate * 256 + q * 64 + kk0;  // global gate row

    __shared__ float h_rep[4][264];
    __shared__ float act_s[256];
    __shared__ float x_s[TT];

    // ---- weights for rows jg0, jg0+1 over k in [64s,64s+64): 128 VGPRs ----
    float4 w0[16], w1[16];
    {
        const float* basek = WT + (size_t)(s * 64) * GD;
        #pragma unroll
        for (int i = 0; i < 16; ++i) {
            const float* p0 = basek + (size_t)(4 * i) * GD + jg0;
            w0[i] = make_float4(p0[0], p0[GD], p0[2 * GD], p0[3 * GD]);
            const float* p1 = p0 + 1;
            w1[i] = make_float4(p1[0], p1[GD], p1[2 * GD], p1[3 * GD]);
        }
    }
    const float wih0 = Wih[jg0], wih1 = Wih[jg0 + 1];
    const float bj0  = bias[jg0], bj1  = bias[jg0 + 1];

    for (int i = tid; i < TT; i += NT) x_s[i] = x[b * TT + i];
    if (tid < 256) {
        float hv = h_init ? h_init[((size_t)b * TT + (TT - 1)) * HD + tid] : 0.f;
        h_rep[tid >> 6][tid & 63] = hv;
    }
    float c = 0.f;               // live in wave q (tid in [64q,64q+64)) only
    bool fast_ok = true;         // sticky per-thread: fast L2 polling until proven broken
    __syncthreads();

    for (int t = 0; t < TT; ++t) {
        const float xt = x_s[t];
        float a0p, a1p, a0q = 0.f, a1q = 0.f;
        if (s == 0) { a0p = fmaf(xt, wih0, bj0); a1p = fmaf(xt, wih1, bj1); }
        else        { a0p = 0.f;                 a1p = 0.f; }
        const float4* h4 = (const float4*)(&h_rep[s][0]);
        #pragma unroll
        for (int i = 0; i < 8; ++i) {
            float4 hv = h4[i];
            a0p = fmaf(hv.x, w0[i].x, a0p); a0p = fmaf(hv.y, w0[i].y, a0p);
            a0p = fmaf(hv.z, w0[i].z, a0p); a0p = fmaf(hv.w, w0[i].w, a0p);
            a1p = fmaf(hv.x, w1[i].x, a1p); a1p = fmaf(hv.y, w1[i].y, a1p);
            a1p = fmaf(hv.z, w1[i].z, a1p); a1p = fmaf(hv.w, w1[i].w, a1p);
        }
        #pragma unroll
        for (int i = 8; i < 16; ++i) {
            float4 hv = h4[i];
            a0q = fmaf(hv.x, w0[i].x, a0q); a0q = fmaf(hv.y, w0[i].y, a0q);
            a0q = fmaf(hv.z, w0[i].z, a0q); a0q = fmaf(hv.w, w0[i].w, a0q);
            a1q = fmaf(hv.x, w1[i].x, a1q); a1q = fmaf(hv.y, w1[i].y, a1q);
            a1q = fmaf(hv.z, w1[i].z, a1q); a1q = fmaf(hv.w, w1[i].w, a1q);
        }
        float a0 = a0p + a0q;
        float a1 = a1p + a1q;
        a0 += __shfl_xor(a0, 1); a0 += __shfl_xor(a0, 2);
        a1 += __shfl_xor(a1, 1); a1 += __shfl_xor(a1, 2);
        if (s == 0) {
            float2 av;
            av.x = (gate == 2) ? tanh_(a0) : sig_(a0);
            av.y = (gate == 2) ? tanh_(a1) : sig_(a1);
            *(float2*)(&act_s[r0]) = av;
        }
        __syncthreads();   // act ready

        const size_t pbase = ((size_t)b * 2 + (t & 1)) * 256;
        if (tid < 256) {
            const int dq = tid >> 6, dk = tid & 63;
            unsigned long long* fs = exf + pbase + tid;
            unsigned long long* ss = exs + pbase + tid;
            if (dq == q) {
                float gi = act_s[dk], gf = act_s[64 + dk], gg = act_s[128 + dk], go = act_s[192 + dk];
                c = fmaf(gf, c, gi * gg);
                float h = go * tanh_(c);
                unsigned long long pk = ((unsigned long long)(unsigned)(t + 1) << 32)
                                      | (unsigned long long)__float_as_uint(h);
                // dual publish: fast (XCD-L2, write-through) + slow (MALL, proven)
                asm volatile("global_store_dwordx2 %0, %1, off sc0"
                             :: "v"(fs), "v"(pk) : "memory");
                __hip_atomic_store(ss, pk, __ATOMIC_RELAXED, __HIP_MEMORY_SCOPE_AGENT);
                h_rep[q][dk] = h;
                states[((size_t)(b * TT + t)) * HD + tid] = h;
            } else {
                const unsigned want = (unsigned)(t + 1);
                unsigned long long v;
                if (fast_ok) {
                    int spins = 0;
                    for (;;) {
                        asm volatile("global_load_dwordx2 %0, %1, off sc0\n\ts_waitcnt vmcnt(0)"
                                     : "=v"(v) : "v"(fs) : "memory");
                        if ((unsigned)(v >> 32) == want) break;
                        if (++spins > 96) { fast_ok = false; break; }   // valve -> slow path
                    }
                }
                if (!fast_ok) {
                    do {
                        v = __hip_atomic_load(ss, __ATOMIC_RELAXED, __HIP_MEMORY_SCOPE_AGENT);
                    } while ((unsigned)(v >> 32) != want);
                }
                h_rep[dq][dk] = __uint_as_float((unsigned)v);
            }
        }
        __syncthreads();   // h replicas ready for t+1
    }
}

// ---------------- proj: ew[b][t]=E·w1, hw[b][t]=Hx·w2 (one wave per row) ----------------
__global__ __launch_bounds__(256) void proj_kernel(
    const float* __restrict__ enc_states, const float* __restrict__ dec_hs,
    const float* __restrict__ linW, float* __restrict__ ew, float* __restrict__ hw)
{
    const int lane = threadIdx.x & 63;
    const int wid  = blockIdx.x * 4 + (threadIdx.x >> 6);
    const int nw   = gridDim.x * 4;
    const float4 w1 = ((const float4*)linW)[lane];
    const float4 w2 = ((const float4*)(linW + HD))[lane];
    for (int o = wid; o < BB * TT; o += nw) {
        float4 v1 = ((const float4*)(enc_states + (size_t)o * HD))[lane];
        float4 v2 = ((const float4*)(dec_hs     + (size_t)o * HD))[lane];
        float s1 = v1.x * w1.x + v1.y * w1.y + v1.z * w1.z + v1.w * w1.w;
        float s2 = v2.x * w2.x + v2.y * w2.y + v2.z * w2.z + v2.w * w2.w;
        #pragma unroll
        for (int m = 1; m < 64; m <<= 1) {
            s1 += __shfl_xor(s1, m);
            s2 += __shfl_xor(s2, m);
        }
        if (lane == 0) { ew[o] = s1; hw[o] = s2; }
    }
}

// ---------------- attention: 32 td rows/block, 4x8 register tile ----------------
#define TD2  32    // td rows per block
#define TEC2 256   // te chunk
#define KC2  32    // k chunk
__global__ __launch_bounds__(256) void attn_kernel(
    const float* __restrict__ enc_states,  // [B][T][H]
    const float* __restrict__ dec_hs,      // [B][T][H]
    const float* __restrict__ ew, const float* __restrict__ hw,
    const float* __restrict__ lin_b,
    float* __restrict__ out)               // [B][T]
{
    const int b   = blockIdx.y;
    const int td0 = blockIdx.x * TD2;
    const int tid = threadIdx.x;
    const int tdt = tid >> 5;   // 0..7 (4 td rows each)
    const int tet = tid & 31;   // 0..31

    __shared__ float Hx[HD][TD2 + 4];   // stride 36: rows 16B-aligned
    __shared__ float E[KC2][TEC2];

    {
        const int td = tid >> 3;
        const int kc = (tid & 7) * 32;
        const float* src = dec_hs + ((size_t)b * TT + td0 + td) * HD + kc;
        #pragma unroll
        for (int qq = 0; qq < 8; ++qq) {
            float4 v = ((const float4*)(src + qq * 4))[0];
            Hx[kc + qq * 4 + 0][td] = v.x;
            Hx[kc + qq * 4 + 1][td] = v.y;
            Hx[kc + qq * 4 + 2][td] = v.z;
            Hx[kc + qq * 4 + 3][td] = v.w;
        }
    }

    float M[4]  = {-1e30f, -1e30f, -1e30f, -1e30f};
    float Nm[4] = {0.f, 0.f, 0.f, 0.f};
    float Dn[4] = {0.f, 0.f, 0.f, 0.f};

    for (int tc = 0; tc < TT / TEC2; ++tc) {
        const int te0 = tc * TEC2;
        float S[4][8] = {{0.f}};
        for (int kc = 0; kc < HD / KC2; ++kc) {
            const int k0 = kc * KC2;
            __syncthreads();
            {   // stage E chunk: thread = te row, 32 consecutive k
                const float* src = enc_states + ((size_t)b * TT + te0 + tid) * HD + k0;
                #pragma unroll
                for (int qq = 0; qq < 8; ++qq) {
                    float4 v = ((const float4*)(src + qq * 4))[0];
                    E[qq * 4 + 0][tid] = v.x;
                    E[qq * 4 + 1][tid] = v.y;
                    E[qq * 4 + 2][tid] = v.z;
                    E[qq * 4 + 3][tid] = v.w;
                }
            }
            __syncthreads();
            #pragma unroll 4
            for (int k = 0; k < KC2; ++k) {
                const float4 hx4 = *(const float4*)(&Hx[k0 + k][tdt * 4]);
                #pragma unroll
                for (int i = 0; i < 8; ++i) {
                    const float e = E[k][tet + 32 * i];
                    S[0][i] = fmaf(hx4.x, e, S[0][i]);
                    S[1][i] = fmaf(hx4.y, e, S[1][i]);
                    S[2][i] = fmaf(hx4.z, e, S[2][i]);
                    S[3][i] = fmaf(hx4.w, e, S[3][i]);
                }
            }
        }
        float ewv[8];
        #pragma unroll
        for (int i = 0; i < 8; ++i) ewv[i] = ew[(size_t)b * TT + te0 + tet + 32 * i];
        #pragma unroll
        for (int r = 0; r < 4; ++r) {
            float cm = S[r][0];
            #pragma unroll
            for (int i = 1; i < 8; ++i) cm = fmaxf(cm, S[r][i]);
            #pragma unroll
            for (int m = 1; m < 32; m <<= 1) cm = fmaxf(cm, __shfl_xor(cm, m));
            const float newM  = fmaxf(M[r], cm);
            const float scale = __expf(M[r] - newM);
            float nl = 0.f, dl = 0.f;
            #pragma unroll
            for (int i = 0; i < 8; ++i) {
                const float p = __expf(S[r][i] - newM);
                dl += p;
                nl = fmaf(p, ewv[i], nl);
            }
            #pragma unroll
            for (int m = 1; m < 32; m <<= 1) {
                nl += __shfl_xor(nl, m);
                dl += __shfl_xor(dl, m);
            }
            Nm[r] = Nm[r] * scale + nl;
            Dn[r] = Dn[r] * scale + dl;
            M[r]  = newM;
        }
    }

    if (tet == 0) {
        const float lb = lin_b[0];
        #pragma unroll
        for (int r = 0; r < 4; ++r) {
            const int td = td0 + tdt * 4 + r;
            out[(size_t)b * TT + td] = Nm[r] / Dn[r] + hw[(size_t)b * TT + td] + lb;
        }
    }
}

extern "C" void kernel_launch(void* const* d_in, const int* in_sizes, int n_in,
                              void* d_out, int out_size, void* d_ws, size_t ws_size,
                              hipStream_t stream)
{
    const float* x    = (const float*)d_in[0];
    const float* eWih = (const float*)d_in[1];
    const float* eWhh = (const float*)d_in[2];
    const float* ebih = (const float*)d_in[3];
    const float* ebhh = (const float*)d_in[4];
    const float* dWih = (const float*)d_in[5];
    const float* dWhh = (const float*)d_in[6];
    const float* dbih = (const float*)d_in[7];
    const float* dbhh = (const float*)d_in[8];
    const float* linW = (const float*)d_in[9];
    const float* linb = (const float*)d_in[10];
    float* out = (float*)d_out;

    float* p = (float*)d_ws;
    float* WTe = p;        p += (size_t)GD * HD;
    float* WTd = p;        p += (size_t)GD * HD;
    float* be  = p;        p += GD;
    float* bd  = p;        p += GD;
    float* enc_states = p; p += (size_t)BB * TT * HD;
    float* dec_hs = p;     p += (size_t)BB * TT * HD;
    float* ew = p;         p += (size_t)BB * TT;
    float* hw = p;         p += (size_t)BB * TT;
    unsigned long long* ex_base = (unsigned long long*)p;   // [4][B][2][256]
    unsigned long long* exf_e = ex_base + 0 * (size_t)BB * 2 * 256;
    unsigned long long* exs_e = ex_base + 1 * (size_t)BB * 2 * 256;
    unsigned long long* exf_d = ex_base + 2 * (size_t)BB * 2 * 256;
    unsigned long long* exs_d = ex_base + 3 * (size_t)BB * 2 * 256;
    p += (size_t)4 * BB * 2 * 256 * 2;

    prep_kernel<<<(GD * HD + 255) / 256, 256, 0, stream>>>(
        eWhh, ebih, ebhh, dWhh, dbih, dbhh, WTe, WTd, be, bd, ex_base);

    {
        const float* hi = nullptr;
        void* args[] = {(void*)&x, (void*)&eWih, (void*)&be, (void*)&WTe,
                        (void*)&hi, (void*)&enc_states, (void*)&exf_e, (void*)&exs_e};
        hipLaunchCooperativeKernel((void*)lstm_scan_coop, dim3(256), dim3(NT),
                                   args, 0, stream);
    }
    {
        const float* hi = enc_states;
        void* args[] = {(void*)&x, (void*)&dWih, (void*)&bd, (void*)&WTd,
                        (void*)&hi, (void*)&dec_hs, (void*)&exf_d, (void*)&exs_d};
        hipLaunchCooperativeKernel((void*)lstm_scan_coop, dim3(256), dim3(NT),
                                   args, 0, stream);
    }

    proj_kernel<<<256, 256, 0, stream>>>(enc_states, dec_hs, linW, ew, hw);
    attn_kernel<<<dim3(TT / TD2, BB), 256, 0, stream>>>(enc_states, dec_hs, ew, hw, linb, out);
}